// Round 12
// baseline (2972.129 us; speedup 1.0000x reference)
//
#include <hip/hip_runtime.h>
#include <hip/hip_bf16.h>

// ---------------------------------------------------------------------------
// MODEL (R0-R11, PASSED): d_out = f32 buffer, layout
// [X_out N*Dout][ref_a E][backref E][e_map E][v_count 1]. Inputs f32/int32
// (runtime detectors adapt if bf16/int64).
// R12: R11 pipeline, but GEMM compile-time-specialized. R11's runtime-branch
// GEMM spilled (VGPR=256, 1.7GB scratch WRITE) -> 1290us/dispatch.
// ---------------------------------------------------------------------------

#define SCAN_BE 1024

__device__ __forceinline__ float bf2f(unsigned short u) {
    return __uint_as_float(((unsigned int)u) << 16);
}

// manual RNE f32->bf16 (no struct address-taking)
__device__ __forceinline__ unsigned short f2bf(float f) {
    unsigned int b = __float_as_uint(f);
    unsigned int r = (b + 0x7FFFu + ((b >> 16) & 1u)) >> 16;
    return (unsigned short)r;
}

__device__ __forceinline__ float4 load4f(const void* p, size_t off, int isbf) {
    if (isbf) {
        ushort4 u = *(const ushort4*)((const unsigned short*)p + off);
        return make_float4(bf2f(u.x), bf2f(u.y), bf2f(u.z), bf2f(u.w));
    }
    return *(const float4*)((const float*)p + off);
}

// flags[0]=1 if float inputs bf16-packed; flags[1]=1 if indices int64.
__global__ void detect_kernel(const unsigned int* __restrict__ Xw,
                              const unsigned int* __restrict__ bw,
                              int* __restrict__ flags) {
    __shared__ int c_bf16, c_i64;
    int t = threadIdx.x;
    if (t == 0) { c_bf16 = 0; c_i64 = 0; }
    __syncthreads();
    int local = 0;
    #pragma unroll
    for (int k = 0; k < 4; k++) {
        unsigned int w = Xw[t * 4 + k];
        unsigned int e = (w >> 7) & 0xFFu;
        if (e >= 96u && e <= 143u) local++;
    }
    atomicAdd(&c_bf16, local);
    atomicAdd(&c_i64, (bw[2 * t + 1] == 0u) ? 1 : 0);
    __syncthreads();
    if (t == 0) {
        flags[0] = (c_bf16 >= 512) ? 1 : 0;
        flags[1] = (c_i64 == 256) ? 1 : 0;
    }
}

__global__ void zero_kernel(float4* __restrict__ p, long long n4) {
    long long i = (long long)blockIdx.x * blockDim.x + threadIdx.x;
    long long stride = (long long)gridDim.x * blockDim.x;
    for (; i < n4; i += stride)
        p[i] = make_float4(0.f, 0.f, 0.f, 0.f);
}

__global__ void zero_i32(int* __restrict__ p, long long n) {
    long long i = (long long)blockIdx.x * blockDim.x + threadIdx.x;
    long long stride = (long long)gridDim.x * blockDim.x;
    for (; i < n; i += stride) p[i] = 0;
}

__global__ void fill_zero_f32(float* __restrict__ p, long long lo, long long hi) {
    long long i = lo + (long long)blockIdx.x * blockDim.x + threadIdx.x;
    long long stride = (long long)gridDim.x * blockDim.x;
    for (; i < hi; i += stride) p[i] = 0.f;
}

// Index outputs as f32.
__global__ void copy_idx_kernel(const int* __restrict__ ref_a,
                                const int* __restrict__ backref,
                                const int* __restrict__ e_map,
                                const int* __restrict__ v_count,
                                const int* __restrict__ flags,
                                float* __restrict__ out,
                                long long base, long long E) {
    long long i = (long long)blockIdx.x * blockDim.x + threadIdx.x;
    const int is64 = flags[1];
    if (i < E) {
        out[base + i] = (float)ref_a[is64 ? 2 * i : i];
    } else if (i < 2 * E) {
        long long k = i - E;
        out[base + i] = (float)backref[is64 ? 2 * k : k];
    } else if (i < 3 * E) {
        out[base + i] = (float)e_map[i - 2 * E];
    } else if (i == 3 * E) {
        out[base + i] = (float)v_count[0];
    }
}

// ---------------- CSR build ----------------
__global__ void hist_kernel(const int* __restrict__ dst,
                            const int* __restrict__ flags,
                            int* __restrict__ counts, long long E) {
    long long i = (long long)blockIdx.x * blockDim.x + threadIdx.x;
    long long stride = (long long)gridDim.x * blockDim.x;
    const int is64 = flags[1];
    for (; i < E; i += stride)
        atomicAdd(&counts[dst[is64 ? 2 * i : i]], 1);
}

__global__ __launch_bounds__(256) void block_reduce_kernel(
    const int* __restrict__ counts, int* __restrict__ bsum, int n) {
    __shared__ int sd[256];
    int b = blockIdx.x, t = threadIdx.x;
    int lo = b * SCAN_BE;
    int hi = lo + SCAN_BE; if (hi > n) hi = n;
    int s = 0;
    for (int i = lo + t; i < hi; i += 256) s += counts[i];
    sd[t] = s;
    __syncthreads();
    for (int d = 128; d > 0; d >>= 1) {
        if (t < d) sd[t] += sd[t + d];
        __syncthreads();
    }
    if (t == 0) bsum[b] = sd[0];
}

__global__ __launch_bounds__(1024) void scan_bsum_kernel(
    int* __restrict__ bsum, int nb, int* __restrict__ offsets, int n) {
    __shared__ int sd[1024];
    int t = threadIdx.x;
    int v = (t < nb) ? bsum[t] : 0;
    sd[t] = v;
    __syncthreads();
    for (int d = 1; d < 1024; d <<= 1) {
        int x = (t >= d) ? sd[t - d] : 0;
        __syncthreads();
        sd[t] += x;
        __syncthreads();
    }
    if (t < nb) bsum[t] = (t == 0) ? 0 : sd[t - 1];
    if (t == 1023) offsets[n] = sd[1023];
}

__global__ __launch_bounds__(256) void block_scan_kernel(
    const int* counts, const int* __restrict__ bsum,
    int* __restrict__ offsets, int* cursor, int n) {
    __shared__ int ts[256];
    int b = blockIdx.x, t = threadIdx.x;
    int base0 = b * SCAN_BE + t * 4;
    int c0 = (base0 + 0 < n) ? counts[base0 + 0] : 0;
    int c1 = (base0 + 1 < n) ? counts[base0 + 1] : 0;
    int c2 = (base0 + 2 < n) ? counts[base0 + 2] : 0;
    int c3 = (base0 + 3 < n) ? counts[base0 + 3] : 0;
    ts[t] = c0 + c1 + c2 + c3;
    __syncthreads();
    for (int d = 1; d < 256; d <<= 1) {
        int x = (t >= d) ? ts[t - d] : 0;
        __syncthreads();
        ts[t] += x;
        __syncthreads();
    }
    int ex = bsum[b] + (t ? ts[t - 1] : 0);
    if (base0 + 0 < n) { offsets[base0 + 0] = ex; cursor[base0 + 0] = ex; } ex += c0;
    if (base0 + 1 < n) { offsets[base0 + 1] = ex; cursor[base0 + 1] = ex; } ex += c1;
    if (base0 + 2 < n) { offsets[base0 + 2] = ex; cursor[base0 + 2] = ex; } ex += c2;
    if (base0 + 3 < n) { offsets[base0 + 3] = ex; cursor[base0 + 3] = ex; }
}

__global__ __launch_bounds__(1024) void scan_kernel(
    const int* counts, int* __restrict__ offsets, int* cursor, int n) {
    __shared__ int part[1024];
    int t = threadIdx.x;
    int chunk = (n + 1023) / 1024;
    int lo = t * chunk;
    int hi = lo + chunk; if (hi > n) hi = n;
    int s = 0;
    for (int i = lo; i < hi; i++) s += counts[i];
    part[t] = s;
    __syncthreads();
    for (int d = 1; d < 1024; d <<= 1) {
        int v = (t >= d) ? part[t - d] : 0;
        __syncthreads();
        part[t] += v;
        __syncthreads();
    }
    int run = (t == 0) ? 0 : part[t - 1];
    for (int i = lo; i < hi; i++) {
        int c = counts[i];
        offsets[i] = run;
        cursor[i]  = run;
        run += c;
    }
    if (t == 1023) offsets[n] = part[1023];
}

__global__ void scatter_kernel(const int* __restrict__ src,
                               const int* __restrict__ dst,
                               const int* __restrict__ flags,
                               int* __restrict__ cursor,
                               int* __restrict__ srcs, long long E) {
    long long i = (long long)blockIdx.x * blockDim.x + threadIdx.x;
    long long stride = (long long)gridDim.x * blockDim.x;
    const int is64 = flags[1];
    for (; i < E; i += stride) {
        long long ei = is64 ? 2 * i : i;
        int d = dst[ei];
        int s = src[ei];
        int pos = atomicAdd(&cursor[d], 1);
        srcs[pos] = s;
    }
}

// ---------------- GEMM (K=128), compile-time store specialization ----------
// STORE_BF16=0: out f32 = X@W + bias (braw non-null).
// STORE_BF16=1: out bf16 = X@W (no bias).
template <int STORE_BF16>
__global__ __launch_bounds__(256) void gemm128t_kernel(
    const void* __restrict__ Xraw, const void* __restrict__ Wraw,
    const float* __restrict__ braw_f, const unsigned short* __restrict__ braw_b,
    const int* __restrict__ flags, void* __restrict__ outp, long long nrows) {
    const int D = 128;
    __shared__ float sX[64][68];
    __shared__ float sW[64][68];

    const long long rbase = (long long)blockIdx.x * 64;
    const int cbase = blockIdx.y * 64;
    const int t  = threadIdx.x;
    const int tx = t & 15;
    const int ty = t >> 4;
    const int isbf = flags[0];

    float acc[4][4] = {};

    for (int kk = 0; kk < 128; kk += 64) {
        #pragma unroll
        for (int i = 0; i < 4; i++) {
            int r  = ty + i * 16;
            int c4 = tx * 4;
            long long grow = rbase + r;
            float4 v = make_float4(0.f, 0.f, 0.f, 0.f);
            if (grow < nrows)
                v = load4f(Xraw, (size_t)grow * D + kk + c4, isbf);
            *(float4*)&sX[r][c4] = v;
            float4 w = load4f(Wraw, (size_t)(kk + r) * D + cbase + c4, isbf);
            *(float4*)&sW[r][c4] = w;
        }
        __syncthreads();

        #pragma unroll
        for (int k4 = 0; k4 < 16; k4++) {
            float4 xv[4], wv[4];
            #pragma unroll
            for (int i = 0; i < 4; i++)
                xv[i] = *(float4*)&sX[ty * 4 + i][k4 * 4];
            #pragma unroll
            for (int i = 0; i < 4; i++)
                wv[i] = *(float4*)&sW[k4 * 4 + i][tx * 4];
            #pragma unroll
            for (int ki = 0; ki < 4; ki++) {
                #pragma unroll
                for (int r = 0; r < 4; r++) {
                    float x = (ki == 0) ? xv[r].x
                            : (ki == 1) ? xv[r].y
                            : (ki == 2) ? xv[r].z
                                        : xv[r].w;
                    acc[r][0] += x * wv[ki].x;
                    acc[r][1] += x * wv[ki].y;
                    acc[r][2] += x * wv[ki].z;
                    acc[r][3] += x * wv[ki].w;
                }
            }
        }
        __syncthreads();
    }

    const long long grow0 = rbase + ty * 4;
    const int gcol0 = cbase + tx * 4;
    if constexpr (STORE_BF16 == 0) {
        float b0, b1, b2, b3;
        if (isbf) {
            b0 = bf2f(braw_b[gcol0 + 0]); b1 = bf2f(braw_b[gcol0 + 1]);
            b2 = bf2f(braw_b[gcol0 + 2]); b3 = bf2f(braw_b[gcol0 + 3]);
        } else {
            b0 = braw_f[gcol0 + 0]; b1 = braw_f[gcol0 + 1];
            b2 = braw_f[gcol0 + 2]; b3 = braw_f[gcol0 + 3];
        }
        float* o = (float*)outp;
        #pragma unroll
        for (int r = 0; r < 4; r++) {
            long long grow = grow0 + r;
            if (grow >= nrows) break;
            float4 v = make_float4(acc[r][0] + b0, acc[r][1] + b1,
                                   acc[r][2] + b2, acc[r][3] + b3);
            *(float4*)(o + (size_t)grow * D + gcol0) = v;
        }
    } else {
        unsigned short* o = (unsigned short*)outp;
        #pragma unroll
        for (int r = 0; r < 4; r++) {
            long long grow = grow0 + r;
            if (grow >= nrows) break;
            ushort4 pk;
            pk.x = f2bf(acc[r][0]); pk.y = f2bf(acc[r][1]);
            pk.z = f2bf(acc[r][2]); pk.w = f2bf(acc[r][3]);
            *(ushort4*)(o + (size_t)grow * D + gcol0) = pk;
        }
    }
}

// Gather-sum bf16 P rows onto out (already XW+b) + ReLU. 32 lanes/node.
__global__ void agg_fuse_kernel(const unsigned short* __restrict__ P,
                                const int* __restrict__ offsets,
                                const int* __restrict__ srcs,
                                float* __restrict__ out, long long N, int D) {
    long long tid = (long long)blockIdx.x * blockDim.x + threadIdx.x;
    long long g = tid >> 5;
    int lane = (int)(tid & 31);
    if (g >= N) return;
    int lo = offsets[g], hi = offsets[g + 1];
    for (int c = lane * 4; c < D; c += 128) {
        float4 acc = make_float4(0.f, 0.f, 0.f, 0.f);
        for (int i = lo; i < hi; i++) {
            int s = srcs[i];
            ushort4 u = *(const ushort4*)(P + (size_t)s * D + c);
            acc.x += bf2f(u.x); acc.y += bf2f(u.y);
            acc.z += bf2f(u.z); acc.w += bf2f(u.w);
        }
        float* o = out + (size_t)g * D + c;
        float4 v = *(const float4*)o;
        v.x += acc.x; v.x = v.x > 0.f ? v.x : 0.f;
        v.y += acc.y; v.y = v.y > 0.f ? v.y : 0.f;
        v.z += acc.z; v.z = v.z > 0.f ? v.z : 0.f;
        v.w += acc.w; v.w = v.w > 0.f ? v.w : 0.f;
        *(float4*)o = v;
    }
}

// ---------------- fallback: atomic path (ws too small; never here) ---------
__global__ void edge_agg_kernel(const void* __restrict__ Xraw,
                                const int* __restrict__ src,
                                const int* __restrict__ dst,
                                const int* __restrict__ flags,
                                float* __restrict__ A,
                                long long E, int D, int row0, int row1) {
    long long tid = (long long)blockIdx.x * blockDim.x + threadIdx.x;
    long long e = tid >> 5;
    int lane = (int)(tid & 31);
    if (e >= E) return;
    const int is64 = flags[1];
    const int isbf = flags[0];
    long long ei = is64 ? 2 * e : e;
    int d = dst[ei];
    if (d < row0 || d >= row1) return;
    int s = src[ei];
    for (int c = lane * 4; c < D; c += 128) {
        float4 v = load4f(Xraw, (size_t)s * D + c, isbf);
        float* a = A + (size_t)(d - row0) * D + c;
        atomicAdd(a + 0, v.x);
        atomicAdd(a + 1, v.y);
        atomicAdd(a + 2, v.z);
        atomicAdd(a + 3, v.w);
    }
}

__global__ __launch_bounds__(256) void gemm_fused_kernel(
    const void* __restrict__ Xraw, const float* __restrict__ A,
    const void* __restrict__ Wraw, const void* __restrict__ Wpraw,
    const void* __restrict__ braw, const int* __restrict__ flags,
    float* __restrict__ out, long long row0, long long rend) {
    const int D = 128;
    __shared__ float sX[64][68];
    __shared__ float sW[64][68];
    const long long rbase = row0 + (long long)blockIdx.x * 64;
    const int cbase = blockIdx.y * 64;
    const int t  = threadIdx.x;
    const int tx = t & 15;
    const int ty = t >> 4;
    const int isbf = flags[0];
    float acc[4][4] = {};
    for (int kk = 0; kk < 256; kk += 64) {
        const bool first = (kk < 128);
        const void* Ws = first ? Wraw : Wpraw;
        const int kc = kk & 127;
        #pragma unroll
        for (int i = 0; i < 4; i++) {
            int r  = ty + i * 16;
            int c4 = tx * 4;
            long long grow = rbase + r;
            float4 v = make_float4(0.f, 0.f, 0.f, 0.f);
            if (grow < rend) {
                if (first) v = load4f(Xraw, (size_t)grow * D + kc + c4, isbf);
                else v = *(const float4*)(A + (size_t)(grow - row0) * D + kc + c4);
            }
            *(float4*)&sX[r][c4] = v;
            float4 w = load4f(Ws, (size_t)(kc + r) * D + cbase + c4, isbf);
            *(float4*)&sW[r][c4] = w;
        }
        __syncthreads();
        #pragma unroll
        for (int k4 = 0; k4 < 16; k4++) {
            float4 xv[4], wv[4];
            #pragma unroll
            for (int i = 0; i < 4; i++) xv[i] = *(float4*)&sX[ty * 4 + i][k4 * 4];
            #pragma unroll
            for (int i = 0; i < 4; i++) wv[i] = *(float4*)&sW[k4 * 4 + i][tx * 4];
            #pragma unroll
            for (int ki = 0; ki < 4; ki++) {
                #pragma unroll
                for (int r = 0; r < 4; r++) {
                    float x = (ki == 0) ? xv[r].x : (ki == 1) ? xv[r].y
                            : (ki == 2) ? xv[r].z : xv[r].w;
                    acc[r][0] += x * wv[ki].x;
                    acc[r][1] += x * wv[ki].y;
                    acc[r][2] += x * wv[ki].z;
                    acc[r][3] += x * wv[ki].w;
                }
            }
        }
        __syncthreads();
    }
    const long long grow0 = rbase + ty * 4;
    const int gcol0 = cbase + tx * 4;
    float b0, b1, b2, b3;
    if (isbf) {
        const unsigned short* bb = (const unsigned short*)braw;
        b0 = bf2f(bb[gcol0 + 0]); b1 = bf2f(bb[gcol0 + 1]);
        b2 = bf2f(bb[gcol0 + 2]); b3 = bf2f(bb[gcol0 + 3]);
    } else {
        const float* bb = (const float*)braw;
        b0 = bb[gcol0 + 0]; b1 = bb[gcol0 + 1];
        b2 = bb[gcol0 + 2]; b3 = bb[gcol0 + 3];
    }
    #pragma unroll
    for (int r = 0; r < 4; r++) {
        long long grow = grow0 + r;
        if (grow >= rend) break;
        float4 v;
        v.x = acc[r][0] + b0; v.x = v.x > 0.f ? v.x : 0.f;
        v.y = acc[r][1] + b1; v.y = v.y > 0.f ? v.y : 0.f;
        v.z = acc[r][2] + b2; v.z = v.z > 0.f ? v.z : 0.f;
        v.w = acc[r][3] + b3; v.w = v.w > 0.f ? v.w : 0.f;
        *(float4*)(out + (size_t)grow * D + gcol0) = v;
    }
}

// ---------------------------------------------------------------------------
extern "C" void kernel_launch(void* const* d_in, const int* in_sizes, int n_in,
                              void* d_out, int out_size, void* d_ws, size_t ws_size,
                              hipStream_t stream) {
    const void* X       = d_in[0];
    const int*  ref_a   = (const int*)d_in[1];
    const int*  backref = (const int*)d_in[2];
    const int*  e_map   = (const int*)d_in[3];
    const int*  v_count = (const int*)d_in[4];
    const void* W       = d_in[5];
    const void* W_prop  = d_in[6];
    const void* bias    = d_in[7];
    float* out = (float*)d_out;

    int Dout = (n_in > 7 && in_sizes[7] > 0) ? in_sizes[7] : 128;
    int Din  = (in_sizes[5] > 0 && in_sizes[5] % Dout == 0)
                   ? in_sizes[5] / Dout : Dout;
    long long N = in_sizes[0] / Din;
    long long E = in_sizes[1];
    long long base = (long long)out_size - 3 * E - 1;
    if (base < 0) base = N * Dout;

    auto align256 = [](size_t x) { return (x + 255) & ~(size_t)255; };
    size_t o_flags = 0;
    size_t o_off   = align256(o_flags + 256);
    size_t o_cnt   = align256(o_off + (size_t)(N + 1) * 4);
    size_t o_bsum  = align256(o_cnt + (size_t)N * 4);
    size_t o_srcs  = align256(o_bsum + 1024 * 4);
    size_t o_P     = align256(o_srcs + (size_t)E * 4);
    size_t need    = o_P + (size_t)N * Din * 2;
    const bool fast = (ws_size >= need) && (Din == 128) && (Dout == 128);

    char* wsb = (char*)d_ws;
    int*            flags   = (int*)(wsb + o_flags);
    int*            offsets = (int*)(wsb + o_off);
    int*            cursor  = (int*)(wsb + o_cnt);
    int*            bsum    = (int*)(wsb + o_bsum);
    int*            srcs    = (int*)(wsb + o_srcs);
    unsigned short* P       = (unsigned short*)(wsb + o_P);

    detect_kernel<<<1, 256, 0, stream>>>((const unsigned int*)X,
                                         (const unsigned int*)backref, flags);

    {   long long total = 3 * E + 1;
        int blocks = (int)((total + 255) / 256);
        copy_idx_kernel<<<blocks, 256, 0, stream>>>(ref_a, backref, e_map,
                                                    v_count, flags, out,
                                                    base, E);
    }

    long long Nw = N;
    long long cap = base / Dout;
    if (cap < Nw) Nw = cap;
    if (N * Dout < base)
        fill_zero_f32<<<2048, 1024, 0, stream>>>(out, N * Dout, base);

    if (fast) {
        // ---- CSR build ----
        zero_i32<<<256, 256, 0, stream>>>(cursor, N);
        hist_kernel<<<2048, 256, 0, stream>>>(backref, flags, cursor, E);
        int nb = (int)((N + SCAN_BE - 1) / SCAN_BE);
        if (nb <= 1024) {
            block_reduce_kernel<<<nb, 256, 0, stream>>>(cursor, bsum, (int)N);
            scan_bsum_kernel<<<1, 1024, 0, stream>>>(bsum, nb, offsets, (int)N);
            block_scan_kernel<<<nb, 256, 0, stream>>>(cursor, bsum, offsets,
                                                      cursor, (int)N);
        } else {
            scan_kernel<<<1, 1024, 0, stream>>>(cursor, offsets, cursor, (int)N);
        }
        scatter_kernel<<<2048, 256, 0, stream>>>(ref_a, backref, flags,
                                                 cursor, srcs, E);
        // ---- P = X @ Wp (bf16), all N rows ----
        {
            dim3 grid((unsigned)((N + 63) / 64), 2);
            gemm128t_kernel<1><<<grid, 256, 0, stream>>>(
                X, W_prop, nullptr, nullptr, flags, P, N);
        }
        // ---- out = X @ W + b (f32), rows [0, Nw) ----
        {
            dim3 grid((unsigned)((Nw + 63) / 64), 2);
            gemm128t_kernel<0><<<grid, 256, 0, stream>>>(
                X, W, (const float*)bias, (const unsigned short*)bias,
                flags, out, Nw);
        }
        // ---- out = relu(out + segsum(P[srcs])) ----
        {
            long long threads = Nw * 32;
            int blocks = (int)((threads + 255) / 256);
            agg_fuse_kernel<<<blocks, 256, 0, stream>>>(P, offsets, srcs,
                                                        out, Nw, Din);
        }
    } else {
        // ---- fallback: chunked atomic path (R9-proven) ----
        float* A = (float*)(wsb + 256);
        size_t avail = (ws_size > 256) ? ws_size - 256 : 0;
        size_t rows_cap = avail / ((size_t)Din * sizeof(float));
        long long rows_per;
        if (rows_cap >= (size_t)Nw) rows_per = Nw > 0 ? Nw : 1;
        else {
            rows_per = (long long)(rows_cap & ~(size_t)63);
            if (rows_per <= 0) rows_per = 64;
        }
        for (long long row0 = 0; row0 < Nw; row0 += rows_per) {
            long long rows = (Nw - row0 < rows_per) ? (Nw - row0) : rows_per;
            long long rend = row0 + rows;
            {   long long n4 = (rows * (long long)Din) / 4;
                int blocks = (int)((n4 + 1023) / 1024);
                if (blocks > 2048) blocks = 2048;
                if (blocks > 0)
                    zero_kernel<<<blocks, 1024, 0, stream>>>((float4*)A, n4);
            }
            {   long long threads = E * 32;
                int blocks = (int)((threads + 255) / 256);
                edge_agg_kernel<<<blocks, 256, 0, stream>>>(X, ref_a, backref,
                                                            flags, A, E, Din,
                                                            (int)row0, (int)rend);
            }
            {   dim3 grid((unsigned)((rows + 63) / 64), 2);
                gemm_fused_kernel<<<grid, 256, 0, stream>>>(X, A, W, W_prop,
                                                            bias, flags, out,
                                                            row0, rend);
            }
        }
    }
}

// Round 13
// 448.212 us; speedup vs baseline: 6.6311x; 6.6311x over previous
//
#include <hip/hip_runtime.h>
#include <hip/hip_bf16.h>

// ---------------------------------------------------------------------------
// MODEL (R0-R12): d_out = f32 buffer, layout
// [X_out N*Dout][ref_a E][backref E][e_map E][v_count 1]. Inputs f32/int32
// (runtime detectors adapt if bf16/int64).
// R13: R10 pipeline VERBATIM (known-good, 659us) + 3-phase grid-wide scan
// (R10's single-block scan was 229us @ 0.15% occupancy; 3-phase proven
// correct in R11/R12). R11/R12's K=128 GEMM restructure is shelved: its
// fully-unrolled 2-iter K-loop spills (VGPR=256, 1.7GB scratch, 1400us).
// ---------------------------------------------------------------------------

#define SCAN_BE 1024

__device__ __forceinline__ float bf2f(unsigned short u) {
    return __uint_as_float(((unsigned int)u) << 16);
}

__device__ __forceinline__ float4 load4f(const void* p, size_t off, int isbf) {
    if (isbf) {
        ushort4 u = *(const ushort4*)((const unsigned short*)p + off);
        return make_float4(bf2f(u.x), bf2f(u.y), bf2f(u.z), bf2f(u.w));
    }
    return *(const float4*)((const float*)p + off);
}

// flags[0]=1 if float inputs bf16-packed; flags[1]=1 if indices int64.
__global__ void detect_kernel(const unsigned int* __restrict__ Xw,
                              const unsigned int* __restrict__ bw,
                              int* __restrict__ flags) {
    __shared__ int c_bf16, c_i64;
    int t = threadIdx.x;
    if (t == 0) { c_bf16 = 0; c_i64 = 0; }
    __syncthreads();
    int local = 0;
    #pragma unroll
    for (int k = 0; k < 4; k++) {
        unsigned int w = Xw[t * 4 + k];
        unsigned int e = (w >> 7) & 0xFFu;
        if (e >= 96u && e <= 143u) local++;
    }
    atomicAdd(&c_bf16, local);
    atomicAdd(&c_i64, (bw[2 * t + 1] == 0u) ? 1 : 0);
    __syncthreads();
    if (t == 0) {
        flags[0] = (c_bf16 >= 512) ? 1 : 0;
        flags[1] = (c_i64 == 256) ? 1 : 0;
    }
}

__global__ void zero_kernel(float4* __restrict__ p, long long n4) {
    long long i = (long long)blockIdx.x * blockDim.x + threadIdx.x;
    long long stride = (long long)gridDim.x * blockDim.x;
    for (; i < n4; i += stride)
        p[i] = make_float4(0.f, 0.f, 0.f, 0.f);
}

__global__ void zero_i32(int* __restrict__ p, long long n) {
    long long i = (long long)blockIdx.x * blockDim.x + threadIdx.x;
    long long stride = (long long)gridDim.x * blockDim.x;
    for (; i < n; i += stride) p[i] = 0;
}

__global__ void fill_zero_f32(float* __restrict__ p, long long lo, long long hi) {
    long long i = lo + (long long)blockIdx.x * blockDim.x + threadIdx.x;
    long long stride = (long long)gridDim.x * blockDim.x;
    for (; i < hi; i += stride) p[i] = 0.f;
}

// Index outputs as f32.
__global__ void copy_idx_kernel(const int* __restrict__ ref_a,
                                const int* __restrict__ backref,
                                const int* __restrict__ e_map,
                                const int* __restrict__ v_count,
                                const int* __restrict__ flags,
                                float* __restrict__ out,
                                long long base, long long E) {
    long long i = (long long)blockIdx.x * blockDim.x + threadIdx.x;
    const int is64 = flags[1];
    if (i < E) {
        out[base + i] = (float)ref_a[is64 ? 2 * i : i];
    } else if (i < 2 * E) {
        long long k = i - E;
        out[base + i] = (float)backref[is64 ? 2 * k : k];
    } else if (i < 3 * E) {
        out[base + i] = (float)e_map[i - 2 * E];
    } else if (i == 3 * E) {
        out[base + i] = (float)v_count[0];
    }
}

// ---------------- CSR build ----------------
__global__ void hist_kernel(const int* __restrict__ dst,
                            const int* __restrict__ flags,
                            int* __restrict__ counts, long long E) {
    long long i = (long long)blockIdx.x * blockDim.x + threadIdx.x;
    long long stride = (long long)gridDim.x * blockDim.x;
    const int is64 = flags[1];
    for (; i < E; i += stride)
        atomicAdd(&counts[dst[is64 ? 2 * i : i]], 1);
}

// Phase A: per-block sums of SCAN_BE counts.
__global__ __launch_bounds__(256) void block_reduce_kernel(
    const int* __restrict__ counts, int* __restrict__ bsum, int n) {
    __shared__ int sd[256];
    int b = blockIdx.x, t = threadIdx.x;
    int lo = b * SCAN_BE;
    int hi = lo + SCAN_BE; if (hi > n) hi = n;
    int s = 0;
    for (int i = lo + t; i < hi; i += 256) s += counts[i];
    sd[t] = s;
    __syncthreads();
    for (int d = 128; d > 0; d >>= 1) {
        if (t < d) sd[t] += sd[t + d];
        __syncthreads();
    }
    if (t == 0) bsum[b] = sd[0];
}

// Phase B: exclusive scan of nb (<=1024) block sums; writes offsets[n]=total.
__global__ __launch_bounds__(1024) void scan_bsum_kernel(
    int* __restrict__ bsum, int nb, int* __restrict__ offsets, int n) {
    __shared__ int sd[1024];
    int t = threadIdx.x;
    int v = (t < nb) ? bsum[t] : 0;
    sd[t] = v;
    __syncthreads();
    for (int d = 1; d < 1024; d <<= 1) {
        int x = (t >= d) ? sd[t - d] : 0;
        __syncthreads();
        sd[t] += x;
        __syncthreads();
    }
    if (t < nb) bsum[t] = (t == 0) ? 0 : sd[t - 1];
    if (t == 1023) offsets[n] = sd[1023];
}

// Phase C: per-block scan; counts aliases cursor (read-before-write per
// thread, disjoint ranges across blocks).
__global__ __launch_bounds__(256) void block_scan_kernel(
    const int* counts, const int* __restrict__ bsum,
    int* __restrict__ offsets, int* cursor, int n) {
    __shared__ int ts[256];
    int b = blockIdx.x, t = threadIdx.x;
    int base0 = b * SCAN_BE + t * 4;
    int c0 = (base0 + 0 < n) ? counts[base0 + 0] : 0;
    int c1 = (base0 + 1 < n) ? counts[base0 + 1] : 0;
    int c2 = (base0 + 2 < n) ? counts[base0 + 2] : 0;
    int c3 = (base0 + 3 < n) ? counts[base0 + 3] : 0;
    ts[t] = c0 + c1 + c2 + c3;
    __syncthreads();
    for (int d = 1; d < 256; d <<= 1) {
        int x = (t >= d) ? ts[t - d] : 0;
        __syncthreads();
        ts[t] += x;
        __syncthreads();
    }
    int ex = bsum[b] + (t ? ts[t - 1] : 0);
    if (base0 + 0 < n) { offsets[base0 + 0] = ex; cursor[base0 + 0] = ex; } ex += c0;
    if (base0 + 1 < n) { offsets[base0 + 1] = ex; cursor[base0 + 1] = ex; } ex += c1;
    if (base0 + 2 < n) { offsets[base0 + 2] = ex; cursor[base0 + 2] = ex; } ex += c2;
    if (base0 + 3 < n) { offsets[base0 + 3] = ex; cursor[base0 + 3] = ex; }
}

// Legacy single-block scan (only if nb > 1024; never on this instance).
__global__ __launch_bounds__(1024) void scan_kernel(
    const int* counts, int* __restrict__ offsets, int* cursor, int n) {
    __shared__ int part[1024];
    int t = threadIdx.x;
    int chunk = (n + 1023) / 1024;
    int lo = t * chunk;
    int hi = lo + chunk; if (hi > n) hi = n;
    int s = 0;
    for (int i = lo; i < hi; i++) s += counts[i];
    part[t] = s;
    __syncthreads();
    for (int d = 1; d < 1024; d <<= 1) {
        int v = (t >= d) ? part[t - d] : 0;
        __syncthreads();
        part[t] += v;
        __syncthreads();
    }
    int run = (t == 0) ? 0 : part[t - 1];
    for (int i = lo; i < hi; i++) {
        int c = counts[i];
        offsets[i] = run;
        cursor[i]  = run;
        run += c;
    }
    if (t == 1023) offsets[n] = part[1023];
}

__global__ void scatter_kernel(const int* __restrict__ src,
                               const int* __restrict__ dst,
                               const int* __restrict__ flags,
                               int* __restrict__ cursor,
                               int* __restrict__ srcs, long long E) {
    long long i = (long long)blockIdx.x * blockDim.x + threadIdx.x;
    long long stride = (long long)gridDim.x * blockDim.x;
    const int is64 = flags[1];
    for (; i < E; i += stride) {
        long long ei = is64 ? 2 * i : i;
        int d = dst[ei];
        int s = src[ei];
        int pos = atomicAdd(&cursor[d], 1);
        srcs[pos] = s;
    }
}

// Gather aggregation: 32-lane group per node, no atomics. (R10 verbatim)
__global__ void csr_agg_kernel(const void* __restrict__ Xraw,
                               const int* __restrict__ offsets,
                               const int* __restrict__ srcs,
                               const int* __restrict__ flags,
                               float* __restrict__ A, int N, int D) {
    int g = (int)(((long long)blockIdx.x * blockDim.x + threadIdx.x) >> 5);
    int lane = threadIdx.x & 31;
    if (g >= N) return;
    const int isbf = flags[0];
    int lo = offsets[g], hi = offsets[g + 1];
    for (int c = lane * 4; c < D; c += 128) {
        float4 acc = make_float4(0.f, 0.f, 0.f, 0.f);
        for (int i = lo; i < hi; i++) {
            int s = srcs[i];
            float4 v = load4f(Xraw, (size_t)s * D + c, isbf);
            acc.x += v.x; acc.y += v.y; acc.z += v.z; acc.w += v.w;
        }
        *(float4*)(A + (size_t)g * D + c) = acc;
    }
}

// ---------------- fallback: atomic aggregation (ws too small) ----------------
__global__ void edge_agg_kernel(const void* __restrict__ Xraw,
                                const int* __restrict__ src,
                                const int* __restrict__ dst,
                                const int* __restrict__ flags,
                                float* __restrict__ A,
                                long long E, int D, int row0, int row1) {
    long long tid = (long long)blockIdx.x * blockDim.x + threadIdx.x;
    long long e = tid >> 5;
    int lane = (int)(tid & 31);
    if (e >= E) return;
    const int is64 = flags[1];
    const int isbf = flags[0];
    long long ei = is64 ? 2 * e : e;
    int d = dst[ei];
    if (d < row0 || d >= row1) return;
    int s = src[ei];
    for (int c = lane * 4; c < D; c += 128) {
        float4 v = load4f(Xraw, (size_t)s * D + c, isbf);
        float* a = A + (size_t)(d - row0) * D + c;
        atomicAdd(a + 0, v.x);
        atomicAdd(a + 1, v.y);
        atomicAdd(a + 2, v.z);
        atomicAdd(a + 3, v.w);
    }
}

// Fused GEMM (Din=Dout=128): out = relu([X|A] @ [W;Wp] + b). (R10 verbatim)
__global__ __launch_bounds__(256) void gemm_fused_kernel(
    const void* __restrict__ Xraw, const float* __restrict__ A,
    const void* __restrict__ Wraw, const void* __restrict__ Wpraw,
    const void* __restrict__ braw, const int* __restrict__ flags,
    float* __restrict__ out, long long row0, long long rend) {
    const int D = 128;
    __shared__ float sX[64][68];
    __shared__ float sW[64][68];

    const long long rbase = row0 + (long long)blockIdx.x * 64;
    const int cbase = blockIdx.y * 64;
    const int t  = threadIdx.x;
    const int tx = t & 15;
    const int ty = t >> 4;
    const int isbf = flags[0];

    float acc[4][4] = {};

    for (int kk = 0; kk < 256; kk += 64) {
        const bool first = (kk < 128);
        const void* Ws = first ? Wraw : Wpraw;
        const int kc = kk & 127;

        #pragma unroll
        for (int i = 0; i < 4; i++) {
            int r  = ty + i * 16;
            int c4 = tx * 4;
            long long grow = rbase + r;
            float4 v = make_float4(0.f, 0.f, 0.f, 0.f);
            if (grow < rend) {
                if (first)
                    v = load4f(Xraw, (size_t)grow * D + kc + c4, isbf);
                else
                    v = *(const float4*)(A + (size_t)(grow - row0) * D + kc + c4);
            }
            *(float4*)&sX[r][c4] = v;
            float4 w = load4f(Ws, (size_t)(kc + r) * D + cbase + c4, isbf);
            *(float4*)&sW[r][c4] = w;
        }
        __syncthreads();

        #pragma unroll
        for (int k4 = 0; k4 < 16; k4++) {
            float4 xv[4], wv[4];
            #pragma unroll
            for (int i = 0; i < 4; i++)
                xv[i] = *(float4*)&sX[ty * 4 + i][k4 * 4];
            #pragma unroll
            for (int i = 0; i < 4; i++)
                wv[i] = *(float4*)&sW[k4 * 4 + i][tx * 4];
            #pragma unroll
            for (int ki = 0; ki < 4; ki++) {
                #pragma unroll
                for (int r = 0; r < 4; r++) {
                    float x = (ki == 0) ? xv[r].x
                            : (ki == 1) ? xv[r].y
                            : (ki == 2) ? xv[r].z
                                        : xv[r].w;
                    acc[r][0] += x * wv[ki].x;
                    acc[r][1] += x * wv[ki].y;
                    acc[r][2] += x * wv[ki].z;
                    acc[r][3] += x * wv[ki].w;
                }
            }
        }
        __syncthreads();
    }

    const long long grow0 = rbase + ty * 4;
    const int gcol0 = cbase + tx * 4;
    float b0, b1, b2, b3;
    if (isbf) {
        const unsigned short* bb = (const unsigned short*)braw;
        b0 = bf2f(bb[gcol0 + 0]); b1 = bf2f(bb[gcol0 + 1]);
        b2 = bf2f(bb[gcol0 + 2]); b3 = bf2f(bb[gcol0 + 3]);
    } else {
        const float* bb = (const float*)braw;
        b0 = bb[gcol0 + 0]; b1 = bb[gcol0 + 1];
        b2 = bb[gcol0 + 2]; b3 = bb[gcol0 + 3];
    }
    #pragma unroll
    for (int r = 0; r < 4; r++) {
        long long grow = grow0 + r;
        if (grow >= rend) break;
        float4 v;
        v.x = acc[r][0] + b0; v.x = v.x > 0.f ? v.x : 0.f;
        v.y = acc[r][1] + b1; v.y = v.y > 0.f ? v.y : 0.f;
        v.z = acc[r][2] + b2; v.z = v.z > 0.f ? v.z : 0.f;
        v.w = acc[r][3] + b3; v.w = v.w > 0.f ? v.w : 0.f;
        *(float4*)(out + (size_t)grow * D + gcol0) = v;
    }
}

// ---------------------------------------------------------------------------
extern "C" void kernel_launch(void* const* d_in, const int* in_sizes, int n_in,
                              void* d_out, int out_size, void* d_ws, size_t ws_size,
                              hipStream_t stream) {
    const void* X       = d_in[0];
    const int*  ref_a   = (const int*)d_in[1];
    const int*  backref = (const int*)d_in[2];
    const int*  e_map   = (const int*)d_in[3];
    const int*  v_count = (const int*)d_in[4];
    const void* W       = d_in[5];
    const void* W_prop  = d_in[6];
    const void* bias    = d_in[7];
    float* out = (float*)d_out;

    int Dout = (n_in > 7 && in_sizes[7] > 0) ? in_sizes[7] : 128;
    int Din  = (in_sizes[5] > 0 && in_sizes[5] % Dout == 0)
                   ? in_sizes[5] / Dout : Dout;
    long long N = in_sizes[0] / Din;
    long long E = in_sizes[1];
    long long base = (long long)out_size - 3 * E - 1;
    if (base < 0) base = N * Dout;

    // ---- workspace layout (R10) + bsum ----
    auto align256 = [](size_t x) { return (x + 255) & ~(size_t)255; };
    size_t o_flags = 0;
    size_t o_off   = align256(o_flags + 256);
    size_t o_cur   = align256(o_off + (size_t)(N + 1) * 4);
    size_t o_bsum  = align256(o_cur + (size_t)N * 4);
    size_t o_srcs  = align256(o_bsum + 1024 * 4);
    size_t o_A     = align256(o_srcs + (size_t)E * 4);
    size_t need    = o_A + (size_t)N * Din * 4;
    const bool use_csr = (ws_size >= need);

    char* wsb = (char*)d_ws;
    int*   flags   = (int*)(wsb + o_flags);
    int*   offsets = (int*)(wsb + o_off);
    int*   cursor  = (int*)(wsb + o_cur);
    int*   bsum    = (int*)(wsb + o_bsum);
    int*   srcs    = (int*)(wsb + o_srcs);
    float* A       = use_csr ? (float*)(wsb + o_A) : (float*)(wsb + 256);

    detect_kernel<<<1, 256, 0, stream>>>((const unsigned int*)X,
                                         (const unsigned int*)backref, flags);

    {   long long total = 3 * E + 1;
        int blocks = (int)((total + 255) / 256);
        copy_idx_kernel<<<blocks, 256, 0, stream>>>(ref_a, backref, e_map,
                                                    v_count, flags, out,
                                                    base, E);
    }

    long long Nw = N;
    long long cap = base / Dout;
    if (cap < Nw) Nw = cap;
    if (N * Dout < base)
        fill_zero_f32<<<2048, 1024, 0, stream>>>(out, N * Dout, base);

    if (use_csr) {
        // ---- CSR build: histogram -> 3-phase scan -> scatter ----
        zero_i32<<<256, 256, 0, stream>>>(cursor, N);          // counts
        hist_kernel<<<2048, 256, 0, stream>>>(backref, flags, cursor, E);
        int nb = (int)((N + SCAN_BE - 1) / SCAN_BE);
        if (nb <= 1024) {
            block_reduce_kernel<<<nb, 256, 0, stream>>>(cursor, bsum, (int)N);
            scan_bsum_kernel<<<1, 1024, 0, stream>>>(bsum, nb, offsets, (int)N);
            block_scan_kernel<<<nb, 256, 0, stream>>>(cursor, bsum, offsets,
                                                      cursor, (int)N);
        } else {
            scan_kernel<<<1, 1024, 0, stream>>>(cursor, offsets, cursor, (int)N);
        }
        scatter_kernel<<<2048, 256, 0, stream>>>(ref_a, backref, flags,
                                                 cursor, srcs, E);
        // ---- gather aggregation, no atomics ----
        {
            long long threads = N * 32;
            int blocks = (int)((threads + 255) / 256);
            csr_agg_kernel<<<blocks, 256, 0, stream>>>(X, offsets, srcs, flags,
                                                       A, (int)N, Din);
        }
        // ---- fused dual-GEMM over all rows ----
        dim3 grid((unsigned)((Nw + 63) / 64), 2);
        gemm_fused_kernel<<<grid, 256, 0, stream>>>(X, A, W, W_prop, bias,
                                                    flags, out, 0, Nw);
    } else {
        // ---- fallback: chunked atomic path (R9-proven) ----
        size_t avail = (ws_size > 256) ? ws_size - 256 : 0;
        size_t rows_cap = avail / ((size_t)Din * sizeof(float));
        long long rows_per;
        if (rows_cap >= (size_t)Nw) rows_per = Nw > 0 ? Nw : 1;
        else {
            rows_per = (long long)(rows_cap & ~(size_t)63);
            if (rows_per <= 0) rows_per = 64;
        }
        for (long long row0 = 0; row0 < Nw; row0 += rows_per) {
            long long rows = (Nw - row0 < rows_per) ? (Nw - row0) : rows_per;
            long long rend = row0 + rows;
            {   long long n4 = (rows * (long long)Din) / 4;
                int blocks = (int)((n4 + 1023) / 1024);
                if (blocks > 2048) blocks = 2048;
                if (blocks > 0)
                    zero_kernel<<<blocks, 1024, 0, stream>>>((float4*)A, n4);
            }
            {   long long threads = E * 32;
                int blocks = (int)((threads + 255) / 256);
                edge_agg_kernel<<<blocks, 256, 0, stream>>>(X, ref_a, backref,
                                                            flags, A, E, Din,
                                                            (int)row0, (int)rend);
            }
            {   dim3 grid((unsigned)((rows + 63) / 64), 2);
                gemm_fused_kernel<<<grid, 256, 0, stream>>>(X, A, W, W_prop,
                                                            bias, flags, out,
                                                            row0, rend);
            }
        }
    }
}

// Round 14
// 378.305 us; speedup vs baseline: 7.8564x; 1.1848x over previous
//
#include <hip/hip_runtime.h>
#include <hip/hip_bf16.h>

// ---------------------------------------------------------------------------
// MODEL (R0-R13): d_out = f32 buffer, layout
// [X_out N*Dout][ref_a E][backref E][e_map E][v_count 1]. Inputs f32/int32
// (runtime detectors adapt if bf16/int64).
// R14 = R13 (448us) + two targeted fixes:
//  (1) XCD-range-partitioned scatter: R13's scatter wrote 106MB for 6.4MB of
//      data (partial-line writebacks from all 8 XCDs dirtying shared lines).
//      2048 blocks = 8 dst-ranges x 256 stripes; block b -> range b&7 so each
//      srcs sub-region is written by ~one XCD and fills lines in its L2.
//  (2) bf16 gather source Xb (ws-gated): halves csr_agg's ~819MB random read.
// ---------------------------------------------------------------------------

#define SCAN_BE 1024

__device__ __forceinline__ float bf2f(unsigned short u) {
    return __uint_as_float(((unsigned int)u) << 16);
}

__device__ __forceinline__ unsigned short f2bf(float f) {
    unsigned int b = __float_as_uint(f);
    unsigned int r = (b + 0x7FFFu + ((b >> 16) & 1u)) >> 16;
    return (unsigned short)r;
}

__device__ __forceinline__ float4 load4f(const void* p, size_t off, int isbf) {
    if (isbf) {
        ushort4 u = *(const ushort4*)((const unsigned short*)p + off);
        return make_float4(bf2f(u.x), bf2f(u.y), bf2f(u.z), bf2f(u.w));
    }
    return *(const float4*)((const float*)p + off);
}

// flags[0]=1 if float inputs bf16-packed; flags[1]=1 if indices int64.
__global__ void detect_kernel(const unsigned int* __restrict__ Xw,
                              const unsigned int* __restrict__ bw,
                              int* __restrict__ flags) {
    __shared__ int c_bf16, c_i64;
    int t = threadIdx.x;
    if (t == 0) { c_bf16 = 0; c_i64 = 0; }
    __syncthreads();
    int local = 0;
    #pragma unroll
    for (int k = 0; k < 4; k++) {
        unsigned int w = Xw[t * 4 + k];
        unsigned int e = (w >> 7) & 0xFFu;
        if (e >= 96u && e <= 143u) local++;
    }
    atomicAdd(&c_bf16, local);
    atomicAdd(&c_i64, (bw[2 * t + 1] == 0u) ? 1 : 0);
    __syncthreads();
    if (t == 0) {
        flags[0] = (c_bf16 >= 512) ? 1 : 0;
        flags[1] = (c_i64 == 256) ? 1 : 0;
    }
}

__global__ void zero_kernel(float4* __restrict__ p, long long n4) {
    long long i = (long long)blockIdx.x * blockDim.x + threadIdx.x;
    long long stride = (long long)gridDim.x * blockDim.x;
    for (; i < n4; i += stride)
        p[i] = make_float4(0.f, 0.f, 0.f, 0.f);
}

__global__ void zero_i32(int* __restrict__ p, long long n) {
    long long i = (long long)blockIdx.x * blockDim.x + threadIdx.x;
    long long stride = (long long)gridDim.x * blockDim.x;
    for (; i < n; i += stride) p[i] = 0;
}

__global__ void fill_zero_f32(float* __restrict__ p, long long lo, long long hi) {
    long long i = lo + (long long)blockIdx.x * blockDim.x + threadIdx.x;
    long long stride = (long long)gridDim.x * blockDim.x;
    for (; i < hi; i += stride) p[i] = 0.f;
}

// X (f32 or bf16) -> Xb (bf16), vectorized 4/thread.
__global__ void xconv_kernel(const void* __restrict__ Xraw,
                             const int* __restrict__ flags,
                             unsigned short* __restrict__ Xb, long long n4) {
    long long i = (long long)blockIdx.x * blockDim.x + threadIdx.x;
    long long stride = (long long)gridDim.x * blockDim.x;
    const int isbf = flags[0];
    for (; i < n4; i += stride) {
        if (isbf) {
            *(ushort4*)(Xb + i * 4) =
                *((const ushort4*)Xraw + i);
        } else {
            float4 v = *((const float4*)Xraw + i);
            ushort4 u;
            u.x = f2bf(v.x); u.y = f2bf(v.y);
            u.z = f2bf(v.z); u.w = f2bf(v.w);
            *(ushort4*)(Xb + i * 4) = u;
        }
    }
}

// Index outputs as f32.
__global__ void copy_idx_kernel(const int* __restrict__ ref_a,
                                const int* __restrict__ backref,
                                const int* __restrict__ e_map,
                                const int* __restrict__ v_count,
                                const int* __restrict__ flags,
                                float* __restrict__ out,
                                long long base, long long E) {
    long long i = (long long)blockIdx.x * blockDim.x + threadIdx.x;
    const int is64 = flags[1];
    if (i < E) {
        out[base + i] = (float)ref_a[is64 ? 2 * i : i];
    } else if (i < 2 * E) {
        long long k = i - E;
        out[base + i] = (float)backref[is64 ? 2 * k : k];
    } else if (i < 3 * E) {
        out[base + i] = (float)e_map[i - 2 * E];
    } else if (i == 3 * E) {
        out[base + i] = (float)v_count[0];
    }
}

// ---------------- CSR build ----------------
__global__ void hist_kernel(const int* __restrict__ dst,
                            const int* __restrict__ flags,
                            int* __restrict__ counts, long long E) {
    long long i = (long long)blockIdx.x * blockDim.x + threadIdx.x;
    long long stride = (long long)gridDim.x * blockDim.x;
    const int is64 = flags[1];
    for (; i < E; i += stride)
        atomicAdd(&counts[dst[is64 ? 2 * i : i]], 1);
}

__global__ __launch_bounds__(256) void block_reduce_kernel(
    const int* __restrict__ counts, int* __restrict__ bsum, int n) {
    __shared__ int sd[256];
    int b = blockIdx.x, t = threadIdx.x;
    int lo = b * SCAN_BE;
    int hi = lo + SCAN_BE; if (hi > n) hi = n;
    int s = 0;
    for (int i = lo + t; i < hi; i += 256) s += counts[i];
    sd[t] = s;
    __syncthreads();
    for (int d = 128; d > 0; d >>= 1) {
        if (t < d) sd[t] += sd[t + d];
        __syncthreads();
    }
    if (t == 0) bsum[b] = sd[0];
}

__global__ __launch_bounds__(1024) void scan_bsum_kernel(
    int* __restrict__ bsum, int nb, int* __restrict__ offsets, int n) {
    __shared__ int sd[1024];
    int t = threadIdx.x;
    int v = (t < nb) ? bsum[t] : 0;
    sd[t] = v;
    __syncthreads();
    for (int d = 1; d < 1024; d <<= 1) {
        int x = (t >= d) ? sd[t - d] : 0;
        __syncthreads();
        sd[t] += x;
        __syncthreads();
    }
    if (t < nb) bsum[t] = (t == 0) ? 0 : sd[t - 1];
    if (t == 1023) offsets[n] = sd[1023];
}

__global__ __launch_bounds__(256) void block_scan_kernel(
    const int* counts, const int* __restrict__ bsum,
    int* __restrict__ offsets, int* cursor, int n) {
    __shared__ int ts[256];
    int b = blockIdx.x, t = threadIdx.x;
    int base0 = b * SCAN_BE + t * 4;
    int c0 = (base0 + 0 < n) ? counts[base0 + 0] : 0;
    int c1 = (base0 + 1 < n) ? counts[base0 + 1] : 0;
    int c2 = (base0 + 2 < n) ? counts[base0 + 2] : 0;
    int c3 = (base0 + 3 < n) ? counts[base0 + 3] : 0;
    ts[t] = c0 + c1 + c2 + c3;
    __syncthreads();
    for (int d = 1; d < 256; d <<= 1) {
        int x = (t >= d) ? ts[t - d] : 0;
        __syncthreads();
        ts[t] += x;
        __syncthreads();
    }
    int ex = bsum[b] + (t ? ts[t - 1] : 0);
    if (base0 + 0 < n) { offsets[base0 + 0] = ex; cursor[base0 + 0] = ex; } ex += c0;
    if (base0 + 1 < n) { offsets[base0 + 1] = ex; cursor[base0 + 1] = ex; } ex += c1;
    if (base0 + 2 < n) { offsets[base0 + 2] = ex; cursor[base0 + 2] = ex; } ex += c2;
    if (base0 + 3 < n) { offsets[base0 + 3] = ex; cursor[base0 + 3] = ex; }
}

__global__ __launch_bounds__(1024) void scan_kernel(
    const int* counts, int* __restrict__ offsets, int* cursor, int n) {
    __shared__ int part[1024];
    int t = threadIdx.x;
    int chunk = (n + 1023) / 1024;
    int lo = t * chunk;
    int hi = lo + chunk; if (hi > n) hi = n;
    int s = 0;
    for (int i = lo; i < hi; i++) s += counts[i];
    part[t] = s;
    __syncthreads();
    for (int d = 1; d < 1024; d <<= 1) {
        int v = (t >= d) ? part[t - d] : 0;
        __syncthreads();
        part[t] += v;
        __syncthreads();
    }
    int run = (t == 0) ? 0 : part[t - 1];
    for (int i = lo; i < hi; i++) {
        int c = counts[i];
        offsets[i] = run;
        cursor[i]  = run;
        run += c;
    }
    if (t == 1023) offsets[n] = part[1023];
}

// XCD-range-partitioned scatter: block b -> dst-range (b&7), stripe (b>>3).
// Each srcs sub-region [offsets[rlo], offsets[rhi]) is written by blocks of
// one XCD (assuming round-robin blockIdx->XCD) -> lines fill in one L2.
__global__ void scatter_xcd_kernel(const int* __restrict__ src,
                                   const int* __restrict__ dst,
                                   const int* __restrict__ flags,
                                   int* __restrict__ cursor,
                                   int* __restrict__ srcs,
                                   long long E, int N, int nstripes) {
    int b = blockIdx.x;
    int r = b & 7;
    int s = b >> 3;
    int rchunk = (N + 7) / 8;
    int rlo = r * rchunk;
    int rhi = rlo + rchunk; if (rhi > N) rhi = N;
    long long e0 = (long long)s * E / nstripes;
    long long e1 = (long long)(s + 1) * E / nstripes;
    const int is64 = flags[1];
    for (long long i = e0 + threadIdx.x; i < e1; i += blockDim.x) {
        long long ei = is64 ? 2 * i : i;
        int d = dst[ei];
        if (d < rlo || d >= rhi) continue;
        int sv = src[ei];
        int pos = atomicAdd(&cursor[d], 1);
        srcs[pos] = sv;
    }
}

// Plain scatter (fallback).
__global__ void scatter_kernel(const int* __restrict__ src,
                               const int* __restrict__ dst,
                               const int* __restrict__ flags,
                               int* __restrict__ cursor,
                               int* __restrict__ srcs, long long E) {
    long long i = (long long)blockIdx.x * blockDim.x + threadIdx.x;
    long long stride = (long long)gridDim.x * blockDim.x;
    const int is64 = flags[1];
    for (; i < E; i += stride) {
        long long ei = is64 ? 2 * i : i;
        int d = dst[ei];
        int s = src[ei];
        int pos = atomicAdd(&cursor[d], 1);
        srcs[pos] = s;
    }
}

// Gather aggregation from bf16 Xb: 32-lane group per node, no atomics.
__global__ void csr_agg_bf16_kernel(const unsigned short* __restrict__ Xb,
                                    const int* __restrict__ offsets,
                                    const int* __restrict__ srcs,
                                    float* __restrict__ A, int N, int D) {
    int g = (int)(((long long)blockIdx.x * blockDim.x + threadIdx.x) >> 5);
    int lane = threadIdx.x & 31;
    if (g >= N) return;
    int lo = offsets[g], hi = offsets[g + 1];
    for (int c = lane * 4; c < D; c += 128) {
        float4 acc = make_float4(0.f, 0.f, 0.f, 0.f);
        for (int i = lo; i < hi; i++) {
            int s = srcs[i];
            ushort4 u = *(const ushort4*)(Xb + (size_t)s * D + c);
            acc.x += bf2f(u.x); acc.y += bf2f(u.y);
            acc.z += bf2f(u.z); acc.w += bf2f(u.w);
        }
        *(float4*)(A + (size_t)g * D + c) = acc;
    }
}

// Gather aggregation from f32 X (fallback when Xb doesn't fit ws).
__global__ void csr_agg_kernel(const void* __restrict__ Xraw,
                               const int* __restrict__ offsets,
                               const int* __restrict__ srcs,
                               const int* __restrict__ flags,
                               float* __restrict__ A, int N, int D) {
    int g = (int)(((long long)blockIdx.x * blockDim.x + threadIdx.x) >> 5);
    int lane = threadIdx.x & 31;
    if (g >= N) return;
    const int isbf = flags[0];
    int lo = offsets[g], hi = offsets[g + 1];
    for (int c = lane * 4; c < D; c += 128) {
        float4 acc = make_float4(0.f, 0.f, 0.f, 0.f);
        for (int i = lo; i < hi; i++) {
            int s = srcs[i];
            float4 v = load4f(Xraw, (size_t)s * D + c, isbf);
            acc.x += v.x; acc.y += v.y; acc.z += v.z; acc.w += v.w;
        }
        *(float4*)(A + (size_t)g * D + c) = acc;
    }
}

// ---------------- fallback: atomic aggregation (ws too small) ----------------
__global__ void edge_agg_kernel(const void* __restrict__ Xraw,
                                const int* __restrict__ src,
                                const int* __restrict__ dst,
                                const int* __restrict__ flags,
                                float* __restrict__ A,
                                long long E, int D, int row0, int row1) {
    long long tid = (long long)blockIdx.x * blockDim.x + threadIdx.x;
    long long e = tid >> 5;
    int lane = (int)(tid & 31);
    if (e >= E) return;
    const int is64 = flags[1];
    const int isbf = flags[0];
    long long ei = is64 ? 2 * e : e;
    int d = dst[ei];
    if (d < row0 || d >= row1) return;
    int s = src[ei];
    for (int c = lane * 4; c < D; c += 128) {
        float4 v = load4f(Xraw, (size_t)s * D + c, isbf);
        float* a = A + (size_t)(d - row0) * D + c;
        atomicAdd(a + 0, v.x);
        atomicAdd(a + 1, v.y);
        atomicAdd(a + 2, v.z);
        atomicAdd(a + 3, v.w);
    }
}

// Fused GEMM (Din=Dout=128): out = relu([X|A] @ [W;Wp] + b). (R10/R13 verbatim)
__global__ __launch_bounds__(256) void gemm_fused_kernel(
    const void* __restrict__ Xraw, const float* __restrict__ A,
    const void* __restrict__ Wraw, const void* __restrict__ Wpraw,
    const void* __restrict__ braw, const int* __restrict__ flags,
    float* __restrict__ out, long long row0, long long rend) {
    const int D = 128;
    __shared__ float sX[64][68];
    __shared__ float sW[64][68];

    const long long rbase = row0 + (long long)blockIdx.x * 64;
    const int cbase = blockIdx.y * 64;
    const int t  = threadIdx.x;
    const int tx = t & 15;
    const int ty = t >> 4;
    const int isbf = flags[0];

    float acc[4][4] = {};

    for (int kk = 0; kk < 256; kk += 64) {
        const bool first = (kk < 128);
        const void* Ws = first ? Wraw : Wpraw;
        const int kc = kk & 127;

        #pragma unroll
        for (int i = 0; i < 4; i++) {
            int r  = ty + i * 16;
            int c4 = tx * 4;
            long long grow = rbase + r;
            float4 v = make_float4(0.f, 0.f, 0.f, 0.f);
            if (grow < rend) {
                if (first)
                    v = load4f(Xraw, (size_t)grow * D + kc + c4, isbf);
                else
                    v = *(const float4*)(A + (size_t)(grow - row0) * D + kc + c4);
            }
            *(float4*)&sX[r][c4] = v;
            float4 w = load4f(Ws, (size_t)(kc + r) * D + cbase + c4, isbf);
            *(float4*)&sW[r][c4] = w;
        }
        __syncthreads();

        #pragma unroll
        for (int k4 = 0; k4 < 16; k4++) {
            float4 xv[4], wv[4];
            #pragma unroll
            for (int i = 0; i < 4; i++)
                xv[i] = *(float4*)&sX[ty * 4 + i][k4 * 4];
            #pragma unroll
            for (int i = 0; i < 4; i++)
                wv[i] = *(float4*)&sW[k4 * 4 + i][tx * 4];
            #pragma unroll
            for (int ki = 0; ki < 4; ki++) {
                #pragma unroll
                for (int r = 0; r < 4; r++) {
                    float x = (ki == 0) ? xv[r].x
                            : (ki == 1) ? xv[r].y
                            : (ki == 2) ? xv[r].z
                                        : xv[r].w;
                    acc[r][0] += x * wv[ki].x;
                    acc[r][1] += x * wv[ki].y;
                    acc[r][2] += x * wv[ki].z;
                    acc[r][3] += x * wv[ki].w;
                }
            }
        }
        __syncthreads();
    }

    const long long grow0 = rbase + ty * 4;
    const int gcol0 = cbase + tx * 4;
    float b0, b1, b2, b3;
    if (isbf) {
        const unsigned short* bb = (const unsigned short*)braw;
        b0 = bf2f(bb[gcol0 + 0]); b1 = bf2f(bb[gcol0 + 1]);
        b2 = bf2f(bb[gcol0 + 2]); b3 = bf2f(bb[gcol0 + 3]);
    } else {
        const float* bb = (const float*)braw;
        b0 = bb[gcol0 + 0]; b1 = bb[gcol0 + 1];
        b2 = bb[gcol0 + 2]; b3 = bb[gcol0 + 3];
    }
    #pragma unroll
    for (int r = 0; r < 4; r++) {
        long long grow = grow0 + r;
        if (grow >= rend) break;
        float4 v;
        v.x = acc[r][0] + b0; v.x = v.x > 0.f ? v.x : 0.f;
        v.y = acc[r][1] + b1; v.y = v.y > 0.f ? v.y : 0.f;
        v.z = acc[r][2] + b2; v.z = v.z > 0.f ? v.z : 0.f;
        v.w = acc[r][3] + b3; v.w = v.w > 0.f ? v.w : 0.f;
        *(float4*)(out + (size_t)grow * D + gcol0) = v;
    }
}

// ---------------------------------------------------------------------------
extern "C" void kernel_launch(void* const* d_in, const int* in_sizes, int n_in,
                              void* d_out, int out_size, void* d_ws, size_t ws_size,
                              hipStream_t stream) {
    const void* X       = d_in[0];
    const int*  ref_a   = (const int*)d_in[1];
    const int*  backref = (const int*)d_in[2];
    const int*  e_map   = (const int*)d_in[3];
    const int*  v_count = (const int*)d_in[4];
    const void* W       = d_in[5];
    const void* W_prop  = d_in[6];
    const void* bias    = d_in[7];
    float* out = (float*)d_out;

    int Dout = (n_in > 7 && in_sizes[7] > 0) ? in_sizes[7] : 128;
    int Din  = (in_sizes[5] > 0 && in_sizes[5] % Dout == 0)
                   ? in_sizes[5] / Dout : Dout;
    long long N = in_sizes[0] / Din;
    long long E = in_sizes[1];
    long long base = (long long)out_size - 3 * E - 1;
    if (base < 0) base = N * Dout;

    // ---- workspace layout ----
    auto align256 = [](size_t x) { return (x + 255) & ~(size_t)255; };
    size_t o_flags = 0;
    size_t o_off   = align256(o_flags + 256);
    size_t o_cur   = align256(o_off + (size_t)(N + 1) * 4);
    size_t o_bsum  = align256(o_cur + (size_t)N * 4);
    size_t o_srcs  = align256(o_bsum + 1024 * 4);
    size_t o_A     = align256(o_srcs + (size_t)E * 4);
    size_t o_Xb    = align256(o_A + (size_t)N * Din * 4);
    size_t need_csr  = o_Xb;                          // without Xb
    size_t need_bf16 = o_Xb + (size_t)N * Din * 2;    // with Xb
    const bool use_csr  = (ws_size >= need_csr);
    const bool use_bf16 = (ws_size >= need_bf16);

    char* wsb = (char*)d_ws;
    int*            flags   = (int*)(wsb + o_flags);
    int*            offsets = (int*)(wsb + o_off);
    int*            cursor  = (int*)(wsb + o_cur);
    int*            bsum    = (int*)(wsb + o_bsum);
    int*            srcs    = (int*)(wsb + o_srcs);
    float*          A       = use_csr ? (float*)(wsb + o_A) : (float*)(wsb + 256);
    unsigned short* Xb      = (unsigned short*)(wsb + o_Xb);

    detect_kernel<<<1, 256, 0, stream>>>((const unsigned int*)X,
                                         (const unsigned int*)backref, flags);

    {   long long total = 3 * E + 1;
        int blocks = (int)((total + 255) / 256);
        copy_idx_kernel<<<blocks, 256, 0, stream>>>(ref_a, backref, e_map,
                                                    v_count, flags, out,
                                                    base, E);
    }

    long long Nw = N;
    long long cap = base / Dout;
    if (cap < Nw) Nw = cap;
    if (N * Dout < base)
        fill_zero_f32<<<2048, 1024, 0, stream>>>(out, N * Dout, base);

    if (use_csr) {
        // ---- CSR build: histogram -> 3-phase scan -> XCD scatter ----
        zero_i32<<<256, 256, 0, stream>>>(cursor, N);          // counts
        hist_kernel<<<2048, 256, 0, stream>>>(backref, flags, cursor, E);
        int nb = (int)((N + SCAN_BE - 1) / SCAN_BE);
        if (nb <= 1024) {
            block_reduce_kernel<<<nb, 256, 0, stream>>>(cursor, bsum, (int)N);
            scan_bsum_kernel<<<1, 1024, 0, stream>>>(bsum, nb, offsets, (int)N);
            block_scan_kernel<<<nb, 256, 0, stream>>>(cursor, bsum, offsets,
                                                      cursor, (int)N);
        } else {
            scan_kernel<<<1, 1024, 0, stream>>>(cursor, offsets, cursor, (int)N);
        }
        {
            const int nstripes = 256;
            scatter_xcd_kernel<<<8 * nstripes, 256, 0, stream>>>(
                ref_a, backref, flags, cursor, srcs, E, (int)N, nstripes);
        }
        // ---- gather aggregation, no atomics ----
        if (use_bf16) {
            long long n4 = (N * (long long)Din) / 4;
            int cblocks = (int)((n4 + 1023) / 1024);
            if (cblocks > 2048) cblocks = 2048;
            xconv_kernel<<<cblocks, 1024, 0, stream>>>(X, flags, Xb, n4);
            long long threads = N * 32;
            int blocks = (int)((threads + 255) / 256);
            csr_agg_bf16_kernel<<<blocks, 256, 0, stream>>>(Xb, offsets, srcs,
                                                            A, (int)N, Din);
        } else {
            long long threads = N * 32;
            int blocks = (int)((threads + 255) / 256);
            csr_agg_kernel<<<blocks, 256, 0, stream>>>(X, offsets, srcs, flags,
                                                       A, (int)N, Din);
        }
        // ---- fused dual-GEMM over all rows ----
        dim3 grid((unsigned)((Nw + 63) / 64), 2);
        gemm_fused_kernel<<<grid, 256, 0, stream>>>(X, A, W, W_prop, bias,
                                                    flags, out, 0, Nw);
    } else {
        // ---- fallback: chunked atomic path (R9-proven) ----
        size_t avail = (ws_size > 256) ? ws_size - 256 : 0;
        size_t rows_cap = avail / ((size_t)Din * sizeof(float));
        long long rows_per;
        if (rows_cap >= (size_t)Nw) rows_per = Nw > 0 ? Nw : 1;
        else {
            rows_per = (long long)(rows_cap & ~(size_t)63);
            if (rows_per <= 0) rows_per = 64;
        }
        for (long long row0 = 0; row0 < Nw; row0 += rows_per) {
            long long rows = (Nw - row0 < rows_per) ? (Nw - row0) : rows_per;
            long long rend = row0 + rows;
            {   long long n4 = (rows * (long long)Din) / 4;
                int blocks = (int)((n4 + 1023) / 1024);
                if (blocks > 2048) blocks = 2048;
                if (blocks > 0)
                    zero_kernel<<<blocks, 1024, 0, stream>>>((float4*)A, n4);
            }
            {   long long threads = E * 32;
                int blocks = (int)((threads + 255) / 256);
                edge_agg_kernel<<<blocks, 256, 0, stream>>>(X, ref_a, backref,
                                                            flags, A, E, Din,
                                                            (int)row0, (int)rend);
            }
            {   dim3 grid((unsigned)((rows + 63) / 64), 2);
                gemm_fused_kernel<<<grid, 256, 0, stream>>>(X, A, W, W_prop,
                                                            bias, flags, out,
                                                            row0, rend);
            }
        }
    }
}